// Round 12
// baseline (1779.698 us; speedup 1.0000x reference)
//
#include <hip/hip_runtime.h>
#include <cstdint>
#include <cstddef>

// Problem constants (match reference setup_inputs)
#define NPTS 16384   // N
#define NSAMP 1024   // SAMPLES
#define KNBR 32      // MAX_NEIGHBORS
#define NCH 128      // C

// ---------------------------------------------------------------------------
// ROUND-15 THEORY: R11 falsified the store-drain theory (deferred writeback
// neutral). Remaining chain audit -> two removable items:
// (1) WINNER COORDS FROM LDS: key now embeds wave(bits14..17)+slot(bits0..3)
//     under md<<32|~orig<<18 (order still (md,~orig); wave/slot only split
//     identical points, impossible). A persistent OWNER thread per wave
//     publishes {wave-best key, winner x,y,z} to LDS each iteration (coords
//     from its own regs/LDS; skipped waves republish cached -- exactness =
//     R10's cached-key argument). Post-barrier: broadcast ds_read_b128
//     (~30 cyc) replaces the px[widx] global load (~200-400 cyc).
// (2) ISSUE CUT: R4/R7/R8-validated v_pk_add/mul_f32 asm for distances
//     (18->8 inst/pair; VGPR budget is 128 here since occupancy is
//     LDS-capped at 1 block/CU -- unlike R7's spill case) + loop-invariant
//     key low-words precomputed per slot.
//
// Prune safety (bit-exact, R10-validated): bd2 <= true min d^2 to any wave
// point; skip => fminf identity => wave key AND winner coords unchanged.
//
// Exactness contract (absmax 0): d = (dx*dx+dy*dy)+dz*dz, contract(off), no
// FMA (pk asm elementwise IEEE; sub == add with neg modifier); md =
// fminf(md,d); argmax tie-break smallest ORIGINAL index via u64 key
// (f32bits(md)<<32)|(orig^0x3FFF)<<18|wave<<14|slot. Morton sort permutes
// slots only. group_kernel: R11-validated, unchanged.
// ---------------------------------------------------------------------------

#define FPS_TPB 1024
#define NCELL 512

typedef float f32x2 __attribute__((ext_vector_type(2)));

#define PR8_FOREACH(X) X(0) X(1) X(2) X(3) X(4) X(5) X(6) X(7)

__global__ __launch_bounds__(FPS_TPB)
void fps_kernel(const float* __restrict__ xyz, float* __restrict__ centroids) {
#pragma clang fp contract(off)
  const int b = blockIdx.x;
  const int t = threadIdx.x;          // 0..1023
  const int lane = t & 63;
  const int wave = t >> 6;            // 0..15
  const float* __restrict__ px = xyz + (size_t)b * NPTS * 3;

  __shared__ float A1[NPTS];                     // 64KB: pass A z / pass B x
  __shared__ float A2[NPTS];                     // 64KB: pass A id / pass B y
  __shared__ unsigned hist[NCELL];
  __shared__ unsigned sbase[NCELL];
  __shared__ unsigned long long s_wkey[2][16];   // parity dbuf (validated)
  __shared__ float4 s_wxyz[2][16];               // per-wave winner coords

  // ================= one-time spatial counting sort (MORTON order) =========
  float zsr[16];
  unsigned idsr[16];
  {
    float xr[16], yr[16], zr[16];
    int keys[16], dstv[16];
#pragma unroll
    for (int i = 0; i < 16; ++i) {
      const int p = i * FPS_TPB + t;
      xr[i] = px[p * 3 + 0];
      yr[i] = px[p * 3 + 1];
      zr[i] = px[p * 3 + 2];
      int cx = (int)(xr[i] * 8.0f); cx = cx < 0 ? 0 : (cx > 7 ? 7 : cx);
      int cy = (int)(yr[i] * 8.0f); cy = cy < 0 ? 0 : (cy > 7 ? 7 : cy);
      int cz = (int)(zr[i] * 8.0f); cz = cz < 0 ? 0 : (cz > 7 ? 7 : cz);
      const int mx = (cx & 1) | ((cx & 2) << 2) | ((cx & 4) << 4);
      const int my = (cy & 1) | ((cy & 2) << 2) | ((cy & 4) << 4);
      const int mz = (cz & 1) | ((cz & 2) << 2) | ((cz & 4) << 4);
      keys[i] = mx | (my << 1) | (mz << 2);   // 0..511
    }
    if (t < NCELL) hist[t] = 0u;
    __syncthreads();
#pragma unroll
    for (int i = 0; i < 16; ++i) atomicAdd(&hist[keys[i]], 1u);
    __syncthreads();
    if (t < NCELL) sbase[t] = hist[t];
    __syncthreads();
    for (int d = 1; d < NCELL; d <<= 1) {       // Hillis-Steele inclusive
      unsigned v = 0u;
      if (t < NCELL && t >= d) v = sbase[t - d];
      __syncthreads();
      if (t < NCELL) sbase[t] += v;
      __syncthreads();
    }
    if (t < NCELL) sbase[t] -= hist[t];         // exclusive base
    __syncthreads();
    if (t < NCELL) hist[t] = 0u;                // running within-cell offsets
    __syncthreads();
#pragma unroll
    for (int i = 0; i < 16; ++i)
      dstv[i] = (int)(sbase[keys[i]] + atomicAdd(&hist[keys[i]], 1u));
#pragma unroll
    for (int i = 0; i < 16; ++i) {
      A1[dstv[i]] = zr[i];
      ((unsigned*)A2)[dstv[i]] = (unsigned)(i * FPS_TPB + t);
    }
    __syncthreads();
#pragma unroll
    for (int i = 0; i < 16; ++i) {
      const int u = t * 16 + i;                 // my sorted slots
      zsr[i] = A1[u];
      idsr[i] = ((unsigned*)A2)[u];
    }
    __syncthreads();                            // all reads done before reuse
#pragma unroll
    for (int i = 0; i < 16; ++i) {
      const int u = dstv[i];
      const int fi = ((u & 15) >> 1) * 2048 + (u >> 4) * 2 + (u & 1);
      A1[fi] = xr[i];
      A2[fi] = yr[i];
    }
    __syncthreads();
  }

  // ========== register state: Z, M, precomputed key low-words ==========
#define DECL_PR(j) f32x2 Z##j, M##j; unsigned LOa##j, LOb##j;
  PR8_FOREACH(DECL_PR)
#undef DECL_PR
#define SET_PR(j)                                                         \
  Z##j = (f32x2){zsr[2 * (j)], zsr[2 * (j) + 1]};                         \
  M##j = (f32x2){1e10f, 1e10f};                                           \
  LOa##j = ((idsr[2 * (j)] ^ 0x3FFFu) << 18) | ((unsigned)wave << 14) |   \
           (unsigned)(2 * (j));                                           \
  LOb##j = ((idsr[2 * (j) + 1] ^ 0x3FFFu) << 18) | ((unsigned)wave << 14) | \
           (unsigned)(2 * (j) + 1);
  PR8_FOREACH(SET_PR)
#undef SET_PR

  // per-thread exact AABB -> per-WAVE exact AABB (uniform)
  float mnx = 1e30f, mxx = -1e30f, mny = 1e30f, mxy = -1e30f,
        mnz = 1e30f, mxz = -1e30f;
#define AABB_PR(j) {                                                  \
    const f32x2 xj = ((const f32x2*)A1)[(j) * 1024 + t];              \
    const f32x2 yj = ((const f32x2*)A2)[(j) * 1024 + t];              \
    mnx = fminf(mnx, fminf(xj.x, xj.y));                              \
    mxx = fmaxf(mxx, fmaxf(xj.x, xj.y));                              \
    mny = fminf(mny, fminf(yj.x, yj.y));                              \
    mxy = fmaxf(mxy, fmaxf(yj.x, yj.y));                              \
    mnz = fminf(mnz, fminf(Z##j.x, Z##j.y));                          \
    mxz = fmaxf(mxz, fmaxf(Z##j.x, Z##j.y)); }
  PR8_FOREACH(AABB_PR)
#undef AABB_PR
#pragma unroll
  for (int off = 1; off < 64; off <<= 1) {
    mnx = fminf(mnx, __shfl_xor(mnx, off));
    mxx = fmaxf(mxx, __shfl_xor(mxx, off));
    mny = fminf(mny, __shfl_xor(mny, off));
    mxy = fmaxf(mxy, __shfl_xor(mxy, off));
    mnz = fminf(mnz, __shfl_xor(mnz, off));
    mxz = fmaxf(mxz, __shfl_xor(mxz, off));
  }

  float lx = px[0], ly = px[1], lz = px[2];
  float svx = lx, svy = ly, svz = lz;   // deferred writeback (thread t)
  bool ow = false;                      // persistent owner flag
  unsigned long long mykc = 0ull;       // owner's cached wave-best key
  float wxr = 0.f, wyr = 0.f, wzr = 0.f;  // owner's cached winner coords
  float bvw = 1e10f;                    // wave cached max md (1st iter updates)

  for (int s = 1; s < NSAMP; ++s) {
    const int par = s & 1;
    // wave-uniform exact box distance^2 (prune; R10-validated)
    const float dxb = fmaxf(fmaxf(mnx - lx, lx - mxx), 0.0f);
    const float dyb = fmaxf(fmaxf(mny - ly, ly - mxy), 0.0f);
    const float dzb = fmaxf(fmaxf(mnz - lz, lz - mxz), 0.0f);
    const float bd2 = (dxb * dxb + dyb * dyb) + dzb * dzb;
    if (!(bd2 > bvw * 1.00001f)) {   // wave-uniform branch -> execz skip
      const f32x2 cx2 = {lx, lx}, cy2 = {ly, ly}, cz2 = {lz, lz};
      // distance update: pk asm (R4/R7/R8-validated bit-exact)
#define UPD_PR(j) {                                                       \
      const f32x2 xj = ((const f32x2*)A1)[(j) * 1024 + t];                \
      const f32x2 yj = ((const f32x2*)A2)[(j) * 1024 + t];                \
      f32x2 dx, dy, dz, sx, sy, sz, s1, s2;                               \
      asm("v_pk_add_f32 %0, %1, %2 neg_lo:[0,1] neg_hi:[0,1]"             \
          : "=v"(dx) : "v"(xj), "v"(cx2));                                \
      asm("v_pk_add_f32 %0, %1, %2 neg_lo:[0,1] neg_hi:[0,1]"             \
          : "=v"(dy) : "v"(yj), "v"(cy2));                                \
      asm("v_pk_add_f32 %0, %1, %2 neg_lo:[0,1] neg_hi:[0,1]"             \
          : "=v"(dz) : "v"(Z##j), "v"(cz2));                              \
      asm("v_pk_mul_f32 %0, %1, %1" : "=v"(sx) : "v"(dx));                \
      asm("v_pk_mul_f32 %0, %1, %1" : "=v"(sy) : "v"(dy));                \
      asm("v_pk_mul_f32 %0, %1, %1" : "=v"(sz) : "v"(dz));                \
      asm("v_pk_add_f32 %0, %1, %2" : "=v"(s1) : "v"(sx), "v"(sy));       \
      asm("v_pk_add_f32 %0, %1, %2" : "=v"(s2) : "v"(s1), "v"(sz));       \
      M##j.x = fminf(M##j.x, s2.x);                                       \
      M##j.y = fminf(M##j.y, s2.y); }
      PR8_FOREACH(UPD_PR)
#undef UPD_PR
      // keys: reg-pair assembly (low words precomputed), 15-node max tree
#define KEYS_PR(j)                                                        \
      const unsigned long long kA##j =                                    \
          ((unsigned long long)__float_as_uint(M##j.x) << 32) | LOa##j;   \
      const unsigned long long kB##j =                                    \
          ((unsigned long long)__float_as_uint(M##j.y) << 32) | LOb##j;   \
      const unsigned long long kp##j = kA##j > kB##j ? kA##j : kB##j;
      PR8_FOREACH(KEYS_PR)
#undef KEYS_PR
      const unsigned long long u0 = kp0 > kp1 ? kp0 : kp1;
      const unsigned long long u1 = kp2 > kp3 ? kp2 : kp3;
      const unsigned long long u2 = kp4 > kp5 ? kp4 : kp5;
      const unsigned long long u3 = kp6 > kp7 ? kp6 : kp7;
      const unsigned long long v0 = u0 > u1 ? u0 : u1;
      const unsigned long long v1 = u2 > u3 ? u2 : u3;
      const unsigned long long myk = v0 > v1 ? v0 : v1;
      // wave butterfly max (6 steps; validated)
      unsigned long long nk = myk;
#pragma unroll
      for (int off = 1; off < 64; off <<= 1) {
        const unsigned long long ok = __shfl_xor(nk, off);
        if (ok > nk) nk = ok;
      }
      ow = (myk == nk);   // exactly one owner (keys globally unique)
      if (ow) {
        mykc = nk;
        const int sl = (int)(nk & 15ull);
        const int jj = sl >> 1;
        const f32x2 xv = ((const f32x2*)A1)[jj * 1024 + t];
        const f32x2 yv = ((const f32x2*)A2)[jj * 1024 + t];
        f32x2 zz = Z0;
        if (jj == 1) zz = Z1;
        if (jj == 2) zz = Z2;
        if (jj == 3) zz = Z3;
        if (jj == 4) zz = Z4;
        if (jj == 5) zz = Z5;
        if (jj == 6) zz = Z6;
        if (jj == 7) zz = Z7;
        wxr = (sl & 1) ? xv.y : xv.x;
        wyr = (sl & 1) ? yv.y : yv.x;
        wzr = (sl & 1) ? zz.y : zz.x;
      }
      bvw = __uint_as_float((unsigned)(nk >> 32));
    }
    // owner publishes key + coords (update: fresh; skip: cached -- exact)
    if (ow) {
      s_wkey[par][wave] = mykc;
      s_wxyz[par][wave] = make_float4(wxr, wyr, wzr, 0.0f);
    }
    __syncthreads();  // the ONLY barrier per iteration (parity dbuf)
    unsigned long long bk = s_wkey[par][lane & 15];
#pragma unroll
    for (int off = 1; off < 16; off <<= 1) {
      const unsigned long long ok = __shfl_xor(bk, off);
      if (ok > bk) bk = ok;
    }
    const int wwave = (int)((bk >> 14) & 15ull);
    // winner coords: uniform LDS address -> broadcast ds_read_b128 (~30cyc)
    const float4 wc = s_wxyz[par][wwave];
    lx = wc.x;
    ly = wc.y;
    lz = wc.z;
    if (s == t) { svx = lx; svy = ly; svz = lz; }  // snapshot, no store
  }

  // single writeback pass: thread t owns centroid t
  float* co = centroids + (size_t)b * NSAMP * 3;
  co[t * 3 + 0] = svx;
  co[t * 3 + 1] = svy;
  co[t * 3 + 2] = svz;
}

// ---------------------------------------------------------------------------
// Kernel 2: ball query + gather. One block per centroid (4096 blocks).
// Super-chunk scan with parity-dbuf masks (R11-validated), unchanged.
// ---------------------------------------------------------------------------
__global__ __launch_bounds__(256) void group_kernel(
    const float* __restrict__ xyz, const float* __restrict__ feat,
    const float* __restrict__ centroids,
    float* __restrict__ gxyz, float* __restrict__ gfeat) {
#pragma clang fp contract(off)
  const int gw = blockIdx.x;            // == b * NSAMP + s
  const int b = gw >> 10;
  const int tid = threadIdx.x;
  const int wave = tid >> 6;
  const int lane = tid & 63;

  const float* px = xyz + (size_t)b * NPTS * 3;
  const float* pc = centroids + (size_t)gw * 3;
  const float cx = pc[0], cy = pc[1], cz = pc[2];
  // float32(0.04): numpy compares f32 sqd against python-double 0.04 demoted
  // to f32. NOT 0.2f*0.2f (that's a different float, 1 ulp larger).
  const float rr = 0.04f;

  __shared__ int sh_idx[KNBR];
  __shared__ float sh_gx[KNBR * 3];
  __shared__ unsigned long long sh_mask[2][4];  // parity dbuf

  int cnt = 0;  // uniform across all 256 threads by construction
  for (int n0 = 0; n0 < NPTS && cnt < KNBR; n0 += 256) {
    const int ci = (n0 >> 8) & 1;
    const int p = n0 + tid;
    const float xx = px[p * 3 + 0];
    const float yy = px[p * 3 + 1];
    const float zz = px[p * 3 + 2];
    const float dx = xx - cx;
    const float dy = yy - cy;
    const float dz = zz - cz;
    const float d = (dx * dx + dy * dy) + dz * dz;  // contract(off): no FMA
    const bool in = d <= rr;
    const unsigned long long mask = __ballot(in);
    if (lane == 0) sh_mask[ci][wave] = mask;
    __syncthreads();  // the ONLY barrier per chunk (parity dbuf)
    const unsigned long long m0 = sh_mask[ci][0];
    const unsigned long long m1 = sh_mask[ci][1];
    const unsigned long long m2 = sh_mask[ci][2];
    const unsigned long long m3 = sh_mask[ci][3];
    int base = cnt;
    if (wave > 0) base += (int)__popcll(m0);
    if (wave > 1) base += (int)__popcll(m1);
    if (wave > 2) base += (int)__popcll(m2);
    const int pos = base + (int)__popcll(mask & ((1ull << lane) - 1ull));
    if (in && pos < KNBR) {
      sh_idx[pos] = p;
      sh_gx[pos * 3 + 0] = dx;
      sh_gx[pos * 3 + 1] = dy;
      sh_gx[pos * 3 + 2] = dz;
    }
    cnt += (int)(__popcll(m0) + __popcll(m1) + __popcll(m2) + __popcll(m3));
  }
  if (cnt == 0 && tid == 0) {  // safety: cannot happen
    sh_idx[0] = 0;
    sh_gx[0] = px[0] - cx;
    sh_gx[1] = px[1] - cy;
    sh_gx[2] = px[2] - cz;
  }
  __syncthreads();

  const int nf0 = (cnt < 1) ? 1 : cnt;
  const int nf = (nf0 < KNBR) ? nf0 : KNBR;
  if (tid < KNBR && tid >= nf) {
    sh_idx[tid] = sh_idx[0];
    sh_gx[tid * 3 + 0] = sh_gx[0];
    sh_gx[tid * 3 + 1] = sh_gx[1];
    sh_gx[tid * 3 + 2] = sh_gx[2];
  }
  __syncthreads();

  float* ox = gxyz + (size_t)gw * KNBR * 3;
  if (tid < KNBR * 3) ox[tid] = sh_gx[tid];

  float* og = gfeat + (size_t)gw * KNBR * NCH;
  const float* pf = feat + (size_t)b * NPTS * NCH;
#pragma unroll
  for (int k = wave; k < KNBR; k += 4) {
    const int row = sh_idx[k];
    const float2 v = ((const float2*)(pf + (size_t)row * NCH))[lane];
    ((float2*)(og + (size_t)k * NCH))[lane] = v;
  }
}

extern "C" void kernel_launch(void* const* d_in, const int* in_sizes, int n_in,
                              void* d_out, int out_size, void* d_ws, size_t ws_size,
                              hipStream_t stream) {
  const float* xyz = (const float*)d_in[0];
  const float* feat = (const float*)d_in[1];
  float* out = (float*)d_out;
  const int B = in_sizes[0] / (NPTS * 3);

  float* centroids = out;                                   // [B,S,3]
  float* gxyz = centroids + (size_t)B * NSAMP * 3;          // [B,S,K,3]
  float* gfeat = gxyz + (size_t)B * NSAMP * KNBR * 3;       // [B,S,K,C]

  fps_kernel<<<B, FPS_TPB, 0, stream>>>(xyz, centroids);
  group_kernel<<<B * NSAMP, 256, 0, stream>>>(xyz, feat, centroids, gxyz,
                                              gfeat);
}

// Round 13
// 1540.112 us; speedup vs baseline: 1.1556x; 1.1556x over previous
//
#include <hip/hip_runtime.h>
#include <cstdint>
#include <cstddef>

// Problem constants (match reference setup_inputs)
#define NPTS 16384   // N
#define NSAMP 1024   // SAMPLES
#define KNBR 32      // MAX_NEIGHBORS
#define NCH 128      // C

// ---------------------------------------------------------------------------
// ROUND-16: REVERT to the R10 kernel (session best: fps 1423us, total 1527us,
// absmax 0). R11 (deferred writeback) was neutral; R12 (LDS winner coords +
// pk-asm update) regressed +260us -- asm operand constraints forced lgkmcnt
// drains per update block, defeating the compiler's ds_read/VALU pipelining,
// and the owner machinery added divergence + an LDS round trip. Per the
// pre-committed R11 decision rule (fps >= 1400 => chain is structural), the
// R10 structure is the measured floor for this algorithm family.
//
// What R10 is: wave-uniform Morton-box lazy pruning of exhaustive FPS.
// - One-time 512-cell Morton counting sort in LDS: each wave's contiguous
//   1024 points form a compact box.
// - Per-wave exact AABB (fmin/fmax + butterflies, one-time).
// - Per iteration: wave-uniform exact box-distance^2 vs the wave's cached
//   max-min-dist (key high bits). If bd2 > bvw*(1+1e-5): the whole wave
//   execz-skips the 16-point update + key build + butterfly (~55% of
//   wave-iters on uniform data; measured VALU/iter 2750 -> 1243 cyc).
// - Skip safety (bit-exact): bd2 <= true min d^2 to any wave point =>
//   every fminf is an identity => md and the cached wave key are unchanged
//   => republishing the cached key is exact. False "update" harmless.
//
// Exactness contract (absmax 0): d = (dx*dx+dy*dy)+dz*dz, contract(off), no
// FMA; md = fminf(md,d); argmax tie-break smallest ORIGINAL index via u64
// key (f32bits(md)<<32)|~origidx (md >= 0 so f32 bits are u32-monotone; ~idx
// => larger key == smaller index on value ties; sort permutes slots only,
// keys carry original indices). Winner coords re-read from ORIGINAL px
// (uniform address -> scalar broadcast load). group_kernel: super-chunk
// ballot scan, one block per centroid (R7-R12 validated).
// ---------------------------------------------------------------------------

#define FPS_TPB 1024
#define NCELL 512

typedef float f32x2 __attribute__((ext_vector_type(2)));

#define PR8_FOREACH(X) X(0) X(1) X(2) X(3) X(4) X(5) X(6) X(7)

__global__ __launch_bounds__(FPS_TPB)
void fps_kernel(const float* __restrict__ xyz, float* __restrict__ centroids) {
#pragma clang fp contract(off)
  const int b = blockIdx.x;
  const int t = threadIdx.x;          // 0..1023
  const int lane = t & 63;
  const int wave = t >> 6;            // 0..15
  const float* __restrict__ px = xyz + (size_t)b * NPTS * 3;

  __shared__ float A1[NPTS];                     // 64KB: pass A z / pass B x
  __shared__ float A2[NPTS];                     // 64KB: pass A id / pass B y
  __shared__ unsigned hist[NCELL];
  __shared__ unsigned sbase[NCELL];
  __shared__ unsigned long long s_wkey[2][16];   // parity dbuf (validated)

  // ================= one-time spatial counting sort (MORTON order) =========
  float zsr[16];
  unsigned idsr[16];
  {
    float xr[16], yr[16], zr[16];
    int keys[16], dstv[16];
#pragma unroll
    for (int i = 0; i < 16; ++i) {
      const int p = i * FPS_TPB + t;
      xr[i] = px[p * 3 + 0];
      yr[i] = px[p * 3 + 1];
      zr[i] = px[p * 3 + 2];
      int cx = (int)(xr[i] * 8.0f); cx = cx < 0 ? 0 : (cx > 7 ? 7 : cx);
      int cy = (int)(yr[i] * 8.0f); cy = cy < 0 ? 0 : (cy > 7 ? 7 : cy);
      int cz = (int)(zr[i] * 8.0f); cz = cz < 0 ? 0 : (cz > 7 ? 7 : cz);
      // Morton interleave (bits 0,3,6 per axis): compact contiguous ranges
      const int mx = (cx & 1) | ((cx & 2) << 2) | ((cx & 4) << 4);
      const int my = (cy & 1) | ((cy & 2) << 2) | ((cy & 4) << 4);
      const int mz = (cz & 1) | ((cz & 2) << 2) | ((cz & 4) << 4);
      keys[i] = mx | (my << 1) | (mz << 2);   // 0..511
    }
    if (t < NCELL) hist[t] = 0u;
    __syncthreads();
#pragma unroll
    for (int i = 0; i < 16; ++i) atomicAdd(&hist[keys[i]], 1u);
    __syncthreads();
    if (t < NCELL) sbase[t] = hist[t];
    __syncthreads();
    for (int d = 1; d < NCELL; d <<= 1) {       // Hillis-Steele inclusive
      unsigned v = 0u;
      if (t < NCELL && t >= d) v = sbase[t - d];
      __syncthreads();
      if (t < NCELL) sbase[t] += v;
      __syncthreads();
    }
    if (t < NCELL) sbase[t] -= hist[t];         // exclusive base
    __syncthreads();
    if (t < NCELL) hist[t] = 0u;                // running within-cell offsets
    __syncthreads();
#pragma unroll
    for (int i = 0; i < 16; ++i)
      dstv[i] = (int)(sbase[keys[i]] + atomicAdd(&hist[keys[i]], 1u));
    // pass A: scatter z + original index by sorted slot; read back mine
#pragma unroll
    for (int i = 0; i < 16; ++i) {
      A1[dstv[i]] = zr[i];
      ((unsigned*)A2)[dstv[i]] = (unsigned)(i * FPS_TPB + t);
    }
    __syncthreads();
#pragma unroll
    for (int i = 0; i < 16; ++i) {
      const int u = t * 16 + i;                 // my sorted slots
      zsr[i] = A1[u];
      idsr[i] = ((unsigned*)A2)[u];
    }
    __syncthreads();                            // all reads done before reuse
    // pass B: scatter x,y into pair layout [j][t] f32x2 (stays for the loop)
#pragma unroll
    for (int i = 0; i < 16; ++i) {
      const int u = dstv[i];
      const int fi = ((u & 15) >> 1) * 2048 + (u >> 4) * 2 + (u & 1);
      A1[fi] = xr[i];
      A2[fi] = yr[i];
    }
    __syncthreads();
  }

  // ================= register state (~60 VGPR) =================
#define DECL_PR(j) f32x2 Z##j, M##j; unsigned IDp##j;
  PR8_FOREACH(DECL_PR)
#undef DECL_PR
#define SET_PR(j)                                                     \
  Z##j = (f32x2){zsr[2 * (j)], zsr[2 * (j) + 1]};                     \
  M##j = (f32x2){1e10f, 1e10f};                                       \
  IDp##j = (idsr[2 * (j)] & 0xFFFFu) | (idsr[2 * (j) + 1] << 16);
  PR8_FOREACH(SET_PR)
#undef SET_PR

  // per-thread exact AABB, then reduce to per-WAVE exact AABB (uniform)
  float mnx = 1e30f, mxx = -1e30f, mny = 1e30f, mxy = -1e30f,
        mnz = 1e30f, mxz = -1e30f;
#define AABB_PR(j) {                                                  \
    const f32x2 xj = ((const f32x2*)A1)[(j) * 1024 + t];              \
    const f32x2 yj = ((const f32x2*)A2)[(j) * 1024 + t];              \
    mnx = fminf(mnx, fminf(xj.x, xj.y));                              \
    mxx = fmaxf(mxx, fmaxf(xj.x, xj.y));                              \
    mny = fminf(mny, fminf(yj.x, yj.y));                              \
    mxy = fmaxf(mxy, fmaxf(yj.x, yj.y));                              \
    mnz = fminf(mnz, fminf(Z##j.x, Z##j.y));                          \
    mxz = fmaxf(mxz, fmaxf(Z##j.x, Z##j.y)); }
  PR8_FOREACH(AABB_PR)
#undef AABB_PR
#pragma unroll
  for (int off = 1; off < 64; off <<= 1) {
    mnx = fminf(mnx, __shfl_xor(mnx, off));
    mxx = fmaxf(mxx, __shfl_xor(mxx, off));
    mny = fminf(mny, __shfl_xor(mny, off));
    mxy = fmaxf(mxy, __shfl_xor(mxy, off));
    mnz = fminf(mnz, __shfl_xor(mnz, off));
    mxz = fmaxf(mxz, __shfl_xor(mxz, off));
  }
  // mnx..mxz now wave-uniform exact bounds over the wave's 1024 points

  float* co = centroids + (size_t)b * NSAMP * 3;
  float lx = px[0], ly = px[1], lz = px[2];
  if (t == 0) { co[0] = lx; co[1] = ly; co[2] = lz; }
  unsigned long long wkc = 0ull;  // wave's cached reduced key (uniform)
  float bvw = 1e10f;              // wave's cached max md (=> 1st iter updates)

  for (int s = 1; s < NSAMP; ++s) {
    const int par = s & 1;
    // wave-uniform exact box distance^2 from centroid to wave AABB
    const float dxb = fmaxf(fmaxf(mnx - lx, lx - mxx), 0.0f);
    const float dyb = fmaxf(fmaxf(mny - ly, ly - mxy), 0.0f);
    const float dzb = fmaxf(fmaxf(mnz - lz, lz - mxz), 0.0f);
    const float bd2 = (dxb * dxb + dyb * dyb) + dzb * dzb;
    unsigned long long wk;
    if (!(bd2 > bvw * 1.00001f)) {   // wave-uniform branch -> execz skip
      const f32x2 cx2 = {lx, lx}, cy2 = {ly, ly}, cz2 = {lz, lz};
#define UPD_PR(j) {                                                   \
      const f32x2 xj = ((const f32x2*)A1)[(j) * 1024 + t];            \
      const f32x2 yj = ((const f32x2*)A2)[(j) * 1024 + t];            \
      const f32x2 dx = xj - cx2, dy = yj - cy2, dz = Z##j - cz2;      \
      const f32x2 dd = (dx * dx + dy * dy) + dz * dz; /* no FMA */    \
      M##j.x = fminf(M##j.x, dd.x);                                   \
      M##j.y = fminf(M##j.y, dd.y); }
      PR8_FOREACH(UPD_PR)
#undef UPD_PR
      unsigned long long nk = 0ull;
#define KEY_PR(j) {                                                   \
      const unsigned long long k1 =                                   \
          ((unsigned long long)__float_as_uint(M##j.x) << 32) |       \
          (unsigned)~(IDp##j & 0xFFFFu);                              \
      const unsigned long long k2 =                                   \
          ((unsigned long long)__float_as_uint(M##j.y) << 32) |       \
          (unsigned)~(IDp##j >> 16);                                  \
      if (k1 > nk) nk = k1;                                           \
      if (k2 > nk) nk = k2; }
      PR8_FOREACH(KEY_PR)
#undef KEY_PR
      // wave butterfly max on u64 key (6 steps; validated pattern)
#pragma unroll
      for (int off = 1; off < 64; off <<= 1) {
        const unsigned long long ok = __shfl_xor(nk, off);
        if (ok > nk) nk = ok;
      }
      wk = nk;
      wkc = nk;
      bvw = __uint_as_float((unsigned)(nk >> 32));
    } else {
      wk = wkc;  // md provably unchanged for every wave point
    }
    if (lane == 0) s_wkey[par][wave] = wk;
    __syncthreads();  // the ONLY barrier per iteration (parity dbuf)
    unsigned long long best = s_wkey[par][lane & 15];
#pragma unroll
    for (int off = 1; off < 16; off <<= 1) {
      const unsigned long long ok = __shfl_xor(best, off);
      if (ok > best) best = ok;
    }
    const unsigned widx = (unsigned)__builtin_amdgcn_readfirstlane(
        (int)(~(unsigned)best));
    // winner coords from ORIGINAL array: uniform -> scalar broadcast load
    lx = px[widx * 3 + 0];
    ly = px[widx * 3 + 1];
    lz = px[widx * 3 + 2];
    if (t == 0) {
      co[s * 3 + 0] = lx;
      co[s * 3 + 1] = ly;
      co[s * 3 + 2] = lz;
    }
  }
}

// ---------------------------------------------------------------------------
// Kernel 2: ball query + gather. One block per centroid (4096 blocks).
// Super-chunk scan (R7-R12 validated, ~100us), unchanged.
// ---------------------------------------------------------------------------
__global__ __launch_bounds__(256) void group_kernel(
    const float* __restrict__ xyz, const float* __restrict__ feat,
    const float* __restrict__ centroids,
    float* __restrict__ gxyz, float* __restrict__ gfeat) {
#pragma clang fp contract(off)
  const int gw = blockIdx.x;            // == b * NSAMP + s
  const int b = gw >> 10;
  const int tid = threadIdx.x;
  const int wave = tid >> 6;
  const int lane = tid & 63;

  const float* px = xyz + (size_t)b * NPTS * 3;
  const float* pc = centroids + (size_t)gw * 3;
  const float cx = pc[0], cy = pc[1], cz = pc[2];
  // float32(0.04): numpy compares f32 sqd against python-double 0.04 demoted
  // to f32. NOT 0.2f*0.2f (that's a different float, 1 ulp larger).
  const float rr = 0.04f;

  __shared__ int sh_idx[KNBR];
  __shared__ float sh_gx[KNBR * 3];
  __shared__ unsigned long long sh_mask[4];

  int cnt = 0;  // uniform across all 256 threads by construction
  for (int n0 = 0; n0 < NPTS && cnt < KNBR; n0 += 256) {
    const int p = n0 + tid;
    const float xx = px[p * 3 + 0];
    const float yy = px[p * 3 + 1];
    const float zz = px[p * 3 + 2];
    const float dx = xx - cx;
    const float dy = yy - cy;
    const float dz = zz - cz;
    const float d = (dx * dx + dy * dy) + dz * dz;  // contract(off): no FMA
    const bool in = d <= rr;
    const unsigned long long mask = __ballot(in);
    if (lane == 0) sh_mask[wave] = mask;
    __syncthreads();
    const unsigned long long m0 = sh_mask[0];
    const unsigned long long m1 = sh_mask[1];
    const unsigned long long m2 = sh_mask[2];
    const unsigned long long m3 = sh_mask[3];
    int base = cnt;
    if (wave > 0) base += (int)__popcll(m0);
    if (wave > 1) base += (int)__popcll(m1);
    if (wave > 2) base += (int)__popcll(m2);
    const int pos = base + (int)__popcll(mask & ((1ull << lane) - 1ull));
    if (in && pos < KNBR) {
      sh_idx[pos] = p;
      sh_gx[pos * 3 + 0] = dx;
      sh_gx[pos * 3 + 1] = dy;
      sh_gx[pos * 3 + 2] = dz;
    }
    cnt += (int)(__popcll(m0) + __popcll(m1) + __popcll(m2) + __popcll(m3));
    __syncthreads();  // protect sh_mask reuse next super-chunk
  }
  if (cnt == 0 && tid == 0) {  // safety: cannot happen
    sh_idx[0] = 0;
    sh_gx[0] = px[0] - cx;
    sh_gx[1] = px[1] - cy;
    sh_gx[2] = px[2] - cz;
  }
  __syncthreads();

  const int nf0 = (cnt < 1) ? 1 : cnt;
  const int nf = (nf0 < KNBR) ? nf0 : KNBR;
  if (tid < KNBR && tid >= nf) {
    sh_idx[tid] = sh_idx[0];
    sh_gx[tid * 3 + 0] = sh_gx[0];
    sh_gx[tid * 3 + 1] = sh_gx[1];
    sh_gx[tid * 3 + 2] = sh_gx[2];
  }
  __syncthreads();

  float* ox = gxyz + (size_t)gw * KNBR * 3;
  if (tid < KNBR * 3) ox[tid] = sh_gx[tid];

  float* og = gfeat + (size_t)gw * KNBR * NCH;
  const float* pf = feat + (size_t)b * NPTS * NCH;
#pragma unroll
  for (int k = wave; k < KNBR; k += 4) {
    const int row = sh_idx[k];
    const float2 v = ((const float2*)(pf + (size_t)row * NCH))[lane];
    ((float2*)(og + (size_t)k * NCH))[lane] = v;
  }
}

extern "C" void kernel_launch(void* const* d_in, const int* in_sizes, int n_in,
                              void* d_out, int out_size, void* d_ws, size_t ws_size,
                              hipStream_t stream) {
  const float* xyz = (const float*)d_in[0];
  const float* feat = (const float*)d_in[1];
  float* out = (float*)d_out;
  const int B = in_sizes[0] / (NPTS * 3);

  float* centroids = out;                                   // [B,S,3]
  float* gxyz = centroids + (size_t)B * NSAMP * 3;          // [B,S,K,3]
  float* gfeat = gxyz + (size_t)B * NSAMP * KNBR * 3;       // [B,S,K,C]

  fps_kernel<<<B, FPS_TPB, 0, stream>>>(xyz, centroids);
  group_kernel<<<B * NSAMP, 256, 0, stream>>>(xyz, feat, centroids, gxyz,
                                              gfeat);
}